// Round 2
// baseline (605.862 us; speedup 1.0000x reference)
//
#include <hip/hip_runtime.h>

typedef unsigned short u16;
typedef unsigned int u32;
typedef __bf16 bf16x8 __attribute__((ext_vector_type(8)));
typedef float floatx4 __attribute__((ext_vector_type(4)));

__device__ __forceinline__ u16 f2bf(float f) {
    u32 u = __float_as_uint(f);
    u = (u + 0x7FFFu + ((u >> 16) & 1u)) >> 16;
    return (u16)u;
}

__device__ __forceinline__ void gld_lds16(const u16* g, u16* l) {
    __builtin_amdgcn_global_load_lds(
        (const __attribute__((address_space(1))) u32*)g,
        (__attribute__((address_space(3))) u32*)l, 16, 0, 0);
}

// ---------------------------------------------------------------------------
// Transpose + fp32->bf16 convert: src is K x M (row-major), dst is M x K.
// ---------------------------------------------------------------------------
__global__ __launch_bounds__(256) void transpose_cvt(
    const float* __restrict__ src, u16* __restrict__ dst, int K, int M)
{
    __shared__ float t[32][33];
    const int bm = blockIdx.x * 32, bk = blockIdx.y * 32;
    const int tx = threadIdx.x, ty = threadIdx.y;
    #pragma unroll
    for (int i = ty; i < 32; i += 8)
        t[i][tx] = src[(long)(bk + i) * M + bm + tx];
    __syncthreads();
    #pragma unroll
    for (int i = ty; i < 32; i += 8)
        dst[(long)(bm + i) * K + bk + tx] = f2bf(t[tx][i]);
}

// ---------------------------------------------------------------------------
// LayerNorm over rows of 1024 fp32 -> bf16. One block (256 thr) per row.
// ---------------------------------------------------------------------------
__global__ __launch_bounds__(256) void ln_kernel(
    const float* __restrict__ x, const float* __restrict__ g,
    const float* __restrict__ bta, u16* __restrict__ out)
{
    const int row = blockIdx.x;
    const int tid = threadIdx.x;
    const float4 v = ((const float4*)(x + (long)row * 1024))[tid];
    float s  = v.x + v.y + v.z + v.w;
    float s2 = v.x*v.x + v.y*v.y + v.z*v.z + v.w*v.w;
    #pragma unroll
    for (int off = 1; off < 64; off <<= 1) {
        s  += __shfl_xor(s, off);
        s2 += __shfl_xor(s2, off);
    }
    __shared__ float red[8];
    const int wave = tid >> 6, lane = tid & 63;
    if (lane == 0) { red[wave] = s; red[4 + wave] = s2; }
    __syncthreads();
    s  = red[0] + red[1] + red[2] + red[3];
    s2 = red[4] + red[5] + red[6] + red[7];
    const float mu   = s * (1.0f / 1024.0f);
    const float var  = s2 * (1.0f / 1024.0f) - mu * mu;
    const float rstd = rsqrtf(var + 1e-5f);
    const int c = tid << 2;
    ushort4 o;
    o.x = f2bf((v.x - mu) * rstd * g[c + 0] + bta[c + 0]);
    o.y = f2bf((v.y - mu) * rstd * g[c + 1] + bta[c + 1]);
    o.z = f2bf((v.z - mu) * rstd * g[c + 2] + bta[c + 2]);
    o.w = f2bf((v.w - mu) * rstd * g[c + 3] + bta[c + 3]);
    ((ushort4*)(out + (long)row * 1024))[tid] = o;
}

// ---------------------------------------------------------------------------
// V transpose per (b,h): (bh, s=2048, d=64) -> (bh, d=64, s=2048), bf16.
// ---------------------------------------------------------------------------
__global__ __launch_bounds__(256) void vtrans_kernel(
    const u16* __restrict__ V, u16* __restrict__ Vt)
{
    __shared__ u16 t[64][72];
    const int bh = blockIdx.y, s0 = blockIdx.x << 6;
    const int tid = threadIdx.x;
    const long base = (long)bh * 2048 * 64;
    const int row = tid >> 2, seg = tid & 3;
    *(uint4*)&t[row][seg << 3] =
        *(const uint4*)(V + base + (long)(s0 + row) * 64 + (seg << 3));
    *(uint4*)&t[row][(seg + 4) << 3] =
        *(const uint4*)(V + base + (long)(s0 + row) * 64 + ((seg + 4) << 3));
    __syncthreads();
    #pragma unroll
    for (int half = 0; half < 2; ++half) {
        const int sl = (seg + (half << 2)) << 3;
        u16 tmp[8];
        #pragma unroll
        for (int j = 0; j < 8; ++j) tmp[j] = t[sl + j][row];
        *(uint4*)(Vt + base + (long)row * 2048 + s0 + sl) = *(uint4*)tmp;
    }
}

// ---------------------------------------------------------------------------
// GEMM: C(N x M) = A(N x K, bf16) * Bt(M x K, bf16)^T. 128x128 tile, BK=32,
// m97 structure: global_load_lds width-16 into unpadded LDS.
// MODE 0: out bf16, fused QKV scatter to (which,B,H,S,hd), bias per segment
// MODE 1: out fp32 row-major, +bias +res
// MODE 2: out bf16 row-major, gelu(v+bias)
// ---------------------------------------------------------------------------
template<int MODE>
__global__ __launch_bounds__(256) void gemm_kernel(
    const u16* __restrict__ A, const u16* __restrict__ Bt,
    const float* __restrict__ bias0, const float* __restrict__ bias1,
    const float* __restrict__ bias2, const float* __restrict__ res,
    void* __restrict__ outv, int K, int M)
{
    __shared__ u16 As[128][32];
    __shared__ u16 Bs[128][32];
    const int tid  = threadIdx.x;
    const int lane = tid & 63, wave = tid >> 6;
    const int wm = (wave >> 1) << 6, wn = (wave & 1) << 6;
    const int lrow = lane & 15, quad = lane >> 4, kq = quad << 3;
    const long rowbase = (long)blockIdx.y * 128;
    const long colbase = (long)blockIdx.x * 128;

    // staging: wave w stages LDS rows [32w,32w+32); lane l -> row +l/4, seg l%4
    const int srow = (wave << 5) + (lane >> 2);
    const int sseg = (lane & 3) << 3;
    const u16* ga0 = A  + (rowbase + srow) * (long)K + sseg;
    const u16* ga1 = ga0 + 16 * (long)K;
    const u16* gb0 = Bt + (colbase + srow) * (long)K + sseg;
    const u16* gb1 = gb0 + 16 * (long)K;
    u16* lA0 = &As[(wave << 5)][0];
    u16* lA1 = &As[(wave << 5) + 16][0];
    u16* lB0 = &Bs[(wave << 5)][0];
    u16* lB1 = &Bs[(wave << 5) + 16][0];

    floatx4 acc[4][4];
    #pragma unroll
    for (int i = 0; i < 4; ++i)
        #pragma unroll
        for (int j = 0; j < 4; ++j)
            acc[i][j] = floatx4{0.f, 0.f, 0.f, 0.f};

    for (int k0 = 0; k0 < K; k0 += 32) {
        __syncthreads();
        gld_lds16(ga0 + k0, lA0);
        gld_lds16(ga1 + k0, lA1);
        gld_lds16(gb0 + k0, lB0);
        gld_lds16(gb1 + k0, lB1);
        __syncthreads();
        bf16x8 af[4], bf[4];
        #pragma unroll
        for (int ms = 0; ms < 4; ++ms)
            af[ms] = *(const bf16x8*)&As[wm + (ms << 4) + lrow][kq];
        #pragma unroll
        for (int ns = 0; ns < 4; ++ns)
            bf[ns] = *(const bf16x8*)&Bs[wn + (ns << 4) + lrow][kq];
        #pragma unroll
        for (int ms = 0; ms < 4; ++ms)
            #pragma unroll
            for (int ns = 0; ns < 4; ++ns)
                acc[ms][ns] = __builtin_amdgcn_mfma_f32_16x16x32_bf16(
                    af[ms], bf[ns], acc[ms][ns], 0, 0, 0);
    }

    #pragma unroll
    for (int ms = 0; ms < 4; ++ms) {
        #pragma unroll
        for (int ns = 0; ns < 4; ++ns) {
            const long col = colbase + wn + (ns << 4) + lrow;
            float bv;
            if constexpr (MODE == 0) {
                const int which = (int)(col >> 10);
                const float* bp = which == 0 ? bias0 : (which == 1 ? bias1 : bias2);
                bv = bp[col & 1023];
            } else {
                bv = bias0[col];
            }
            #pragma unroll
            for (int r = 0; r < 4; ++r) {
                const long row = rowbase + wm + (ms << 4) + (quad << 2) + r;
                float v = acc[ms][ns][r] + bv;
                if constexpr (MODE == 0) {
                    const long which = col >> 10;
                    const long b = row >> 11, s = row & 2047;
                    const long h = (col >> 6) & 15, d = col & 63;
                    ((u16*)outv)[which * 4194304 + (((b << 4) + h) * 2048 + s) * 64 + d] = f2bf(v);
                } else if constexpr (MODE == 1) {
                    const long idx = row * M + col;
                    ((float*)outv)[idx] = v + res[idx];
                } else {
                    const float gl = 0.5f * v * (1.0f + erff(v * 0.70710678118f));
                    ((u16*)outv)[row * M + col] = f2bf(gl);
                }
            }
        }
    }
}

// ---------------------------------------------------------------------------
// Flash attention, barrier-free. Q,K in (bh, s, 64) bf16; Vt in (bh, 64, s).
// One wave = 16 queries; block = 4 independent waves (64 q). S^T trick:
// mfma(kf, qf) -> S^T[key][q], q = lane&15 per lane -> softmax is in-lane
// trees + 2 shfl_xor. P -> A-operand via 16 bpermutes. No LDS, no barriers.
// ---------------------------------------------------------------------------
__global__ __launch_bounds__(256, 4) void attn_kernel(
    const u16* __restrict__ Q, const u16* __restrict__ Kp,
    const u16* __restrict__ Vt, u16* __restrict__ O)
{
    const int tid = threadIdx.x, lane = tid & 63, wave = tid >> 6;
    const int lrow = lane & 15, quad = lane >> 4, kq = quad << 3;
    const int bh = blockIdx.y;
    const long kvbase = (long)bh * 2048 * 64;
    const int q0 = (blockIdx.x << 6) + (wave << 4);

    const u16* qrow = Q + kvbase + (long)(q0 + lrow) * 64;
    const bf16x8 qf0 = *(const bf16x8*)(qrow + kq);
    const bf16x8 qf1 = *(const bf16x8*)(qrow + 32 + kq);

    floatx4 oacc[4];
    #pragma unroll
    for (int i = 0; i < 4; ++i) oacc[i] = floatx4{0.f, 0.f, 0.f, 0.f};
    float mrun = -3e38f, lrun = 0.f;

    for (int kv0 = 0; kv0 < 2048; kv0 += 64) {
        // --- QK^T as S^T: per lane, 16 keys of query lrow ---
        float sc[4][4];
        #pragma unroll
        for (int ns = 0; ns < 4; ++ns) {
            const u16* kr = Kp + kvbase + (long)(kv0 + (ns << 4) + lrow) * 64;
            floatx4 c = floatx4{0.f, 0.f, 0.f, 0.f};
            c = __builtin_amdgcn_mfma_f32_16x16x32_bf16(*(const bf16x8*)(kr + kq),      qf0, c, 0, 0, 0);
            c = __builtin_amdgcn_mfma_f32_16x16x32_bf16(*(const bf16x8*)(kr + 32 + kq), qf1, c, 0, 0, 0);
            #pragma unroll
            for (int r = 0; r < 4; ++r) sc[ns][r] = c[r] * 0.125f;
        }
        // --- online softmax (per-lane scalars; reduce in-lane + 2 shfls) ---
        float mt = sc[0][0];
        #pragma unroll
        for (int ns = 0; ns < 4; ++ns)
            #pragma unroll
            for (int r = 0; r < 4; ++r) mt = fmaxf(mt, sc[ns][r]);
        mt = fmaxf(mt, __shfl_xor(mt, 16));
        mt = fmaxf(mt, __shfl_xor(mt, 32));
        const float mnew  = fmaxf(mrun, mt);
        const float alpha = __expf(mrun - mnew);
        mrun = mnew;
        float p[4][4];
        float rs = 0.f;
        #pragma unroll
        for (int ns = 0; ns < 4; ++ns)
            #pragma unroll
            for (int r = 0; r < 4; ++r) {
                p[ns][r] = __expf(sc[ns][r] - mnew);
                rs += p[ns][r];
            }
        rs += __shfl_xor(rs, 16);
        rs += __shfl_xor(rs, 32);
        lrun = lrun * alpha + rs;

        // --- pack P to bf16 pairs: pk[ns][h] = keys ns*16+quad*4+{2h,2h+1} ---
        u32 pk[4][2];
        #pragma unroll
        for (int ns = 0; ns < 4; ++ns)
            #pragma unroll
            for (int h = 0; h < 2; ++h)
                pk[ns][h] = __builtin_amdgcn_perm(
                    __float_as_uint(p[ns][2*h + 1]) + 0x8000u,
                    __float_as_uint(p[ns][2*h])     + 0x8000u, 0x07060302u);

        // --- transform S^T regs -> P A-operand (keys quad*8+j) via shuffles ---
        const int a0 = ((quad & 1) << 5) + lrow;
        union { u32 u[4]; bf16x8 v; } pf[2];
        #pragma unroll
        for (int cs = 0; cs < 2; ++cs) {
            const u32 x0 = (u32)__shfl((int)pk[2*cs][0],     a0);
            const u32 x1 = (u32)__shfl((int)pk[2*cs][1],     a0);
            const u32 x2 = (u32)__shfl((int)pk[2*cs][0],     a0 + 16);
            const u32 x3 = (u32)__shfl((int)pk[2*cs][1],     a0 + 16);
            const u32 y0 = (u32)__shfl((int)pk[2*cs + 1][0], a0);
            const u32 y1 = (u32)__shfl((int)pk[2*cs + 1][1], a0);
            const u32 y2 = (u32)__shfl((int)pk[2*cs + 1][0], a0 + 16);
            const u32 y3 = (u32)__shfl((int)pk[2*cs + 1][1], a0 + 16);
            const bool hi = quad >= 2;
            pf[cs].u[0] = hi ? y0 : x0;
            pf[cs].u[1] = hi ? y1 : x1;
            pf[cs].u[2] = hi ? y2 : x2;
            pf[cs].u[3] = hi ? y3 : x3;
        }

        // --- rescale + PV accumulate: O[q][d], q = quad*4+r ---
        float al[4];
        #pragma unroll
        for (int r = 0; r < 4; ++r) al[r] = __shfl(alpha, (quad << 2) + r);
        #pragma unroll
        for (int ns = 0; ns < 4; ++ns) {
            #pragma unroll
            for (int r = 0; r < 4; ++r) oacc[ns][r] *= al[r];
            const u16* vr = Vt + kvbase + (long)((ns << 4) + lrow) * 2048 + kv0;
            oacc[ns] = __builtin_amdgcn_mfma_f32_16x16x32_bf16(
                pf[0].v, *(const bf16x8*)(vr + kq),      oacc[ns], 0, 0, 0);
            oacc[ns] = __builtin_amdgcn_mfma_f32_16x16x32_bf16(
                pf[1].v, *(const bf16x8*)(vr + 32 + kq), oacc[ns], 0, 0, 0);
        }
    }

    float linv[4];
    #pragma unroll
    for (int r = 0; r < 4; ++r)
        linv[r] = 1.0f / __shfl(lrun, (quad << 2) + r);
    const int b = bh >> 4, h = bh & 15;
    #pragma unroll
    for (int ns = 0; ns < 4; ++ns)
        #pragma unroll
        for (int r = 0; r < 4; ++r) {
            const long token = (long)b * 2048 + q0 + (quad << 2) + r;
            O[token * 1024 + (h << 6) + (ns << 4) + lrow] = f2bf(oacc[ns][r] * linv[r]);
        }
}

// ---------------------------------------------------------------------------
// Host launcher
// ---------------------------------------------------------------------------
extern "C" void kernel_launch(void* const* d_in, const int* in_sizes, int n_in,
                              void* d_out, int out_size, void* d_ws, size_t ws_size,
                              hipStream_t stream)
{
    const float* x     = (const float*)d_in[0];
    const float* ln1_g = (const float*)d_in[1];
    const float* ln1_b = (const float*)d_in[2];
    const float* wq    = (const float*)d_in[3];
    const float* bq    = (const float*)d_in[4];
    const float* wk    = (const float*)d_in[5];
    const float* bk    = (const float*)d_in[6];
    const float* wv    = (const float*)d_in[7];
    const float* bv    = (const float*)d_in[8];
    const float* wo    = (const float*)d_in[9];
    const float* bo    = (const float*)d_in[10];
    const float* w1    = (const float*)d_in[11];
    const float* b1    = (const float*)d_in[12];
    const float* w2    = (const float*)d_in[13];
    const float* b2    = (const float*)d_in[14];
    const float* ln2_g = (const float*)d_in[15];
    const float* ln2_b = (const float*)d_in[16];
    float* out = (float*)d_out;

    char* w = (char*)d_ws;
    const size_t MB = 1024 * 1024;
    u16*   wqkvt = (u16*)(w + 0);        // [0,6) MB: wq^T|wk^T|wv^T (3072x1024)
    u16*   wot   = (u16*)(w + 6  * MB);  // [6,8)
    u16*   w1t   = (u16*)(w + 8  * MB);  // [8,16)
    u16*   w2t   = (u16*)(w + 16 * MB);  // [16,24)
    u16*   h1    = (u16*)(w + 24 * MB);  // [24,32): ln1 out -> attn out -> ln2 out
    u16*   qkvb  = (u16*)(w + 32 * MB);  // [32,56): Q|K|V (bh,s,d)
    u16*   vtb   = (u16*)(w + 56 * MB);  // [56,64): V^T (bh,d,s)
    float* x1    = (float*)(w + 64 * MB);// [64,80): fp32 residual-1 output
    u16*   ffb   = (u16*)(w + 32 * MB);  // [32,64): FF hidden (reuses qkv/vtb)
    u16*   qb = qkvb;
    u16*   kb = qkvb + 4194304;
    u16*   vb = qkvb + 8388608;

    const dim3 tb(32, 8);
    transpose_cvt<<<dim3(32, 32),  tb, 0, stream>>>(wq, wqkvt,            1024, 1024);
    transpose_cvt<<<dim3(32, 32),  tb, 0, stream>>>(wk, wqkvt + 1048576,  1024, 1024);
    transpose_cvt<<<dim3(32, 32),  tb, 0, stream>>>(wv, wqkvt + 2097152,  1024, 1024);
    transpose_cvt<<<dim3(32, 32),  tb, 0, stream>>>(wo, wot,              1024, 1024);
    transpose_cvt<<<dim3(128, 32), tb, 0, stream>>>(w1, w1t,              1024, 4096);
    transpose_cvt<<<dim3(32, 128), tb, 0, stream>>>(w2, w2t,              4096, 1024);

    ln_kernel<<<4096, 256, 0, stream>>>(x, ln1_g, ln1_b, h1);

    gemm_kernel<0><<<dim3(24, 32), 256, 0, stream>>>(
        h1, wqkvt, bq, bk, bv, nullptr, qkvb, 1024, 3072);

    vtrans_kernel<<<dim3(32, 32), 256, 0, stream>>>(vb, vtb);

    attn_kernel<<<dim3(32, 32), 256, 0, stream>>>(qb, kb, vtb, h1);

    gemm_kernel<1><<<dim3(8, 32), 256, 0, stream>>>(
        h1, wot, bo, nullptr, nullptr, x, x1, 1024, 1024);

    ln_kernel<<<4096, 256, 0, stream>>>(x1, ln2_g, ln2_b, h1);

    gemm_kernel<2><<<dim3(32, 32), 256, 0, stream>>>(
        h1, w1t, b1, nullptr, nullptr, nullptr, ffb, 1024, 4096);

    gemm_kernel<1><<<dim3(8, 32), 256, 0, stream>>>(
        ffb, w2t, b2, nullptr, nullptr, x1, out, 4096, 1024);
}

// Round 3
// 436.347 us; speedup vs baseline: 1.3885x; 1.3885x over previous
//
#include <hip/hip_runtime.h>

typedef unsigned short u16;
typedef unsigned int u32;
typedef __bf16 bf16x8 __attribute__((ext_vector_type(8)));
typedef float floatx4 __attribute__((ext_vector_type(4)));

__device__ __forceinline__ u16 f2bf(float f) {
    u32 u = __float_as_uint(f);
    u = (u + 0x7FFFu + ((u >> 16) & 1u)) >> 16;
    return (u16)u;
}

__device__ __forceinline__ void gld_lds16(const u16* g, u16* l) {
    __builtin_amdgcn_global_load_lds(
        (const __attribute__((address_space(1))) u32*)g,
        (__attribute__((address_space(3))) u32*)l, 16, 0, 0);
}

// ---------------------------------------------------------------------------
// Transpose + fp32->bf16 convert: src is K x M (row-major), dst is M x K.
// ---------------------------------------------------------------------------
__global__ __launch_bounds__(256) void transpose_cvt(
    const float* __restrict__ src, u16* __restrict__ dst, int K, int M)
{
    __shared__ float t[32][33];
    const int bm = blockIdx.x * 32, bk = blockIdx.y * 32;
    const int tx = threadIdx.x, ty = threadIdx.y;
    #pragma unroll
    for (int i = ty; i < 32; i += 8)
        t[i][tx] = src[(long)(bk + i) * M + bm + tx];
    __syncthreads();
    #pragma unroll
    for (int i = ty; i < 32; i += 8)
        dst[(long)(bm + i) * K + bk + tx] = f2bf(t[tx][i]);
}

// ---------------------------------------------------------------------------
// LayerNorm over rows of 1024 fp32 -> bf16. One block (256 thr) per row.
// ---------------------------------------------------------------------------
__global__ __launch_bounds__(256) void ln_kernel(
    const float* __restrict__ x, const float* __restrict__ g,
    const float* __restrict__ bta, u16* __restrict__ out)
{
    const int row = blockIdx.x;
    const int tid = threadIdx.x;
    const float4 v = ((const float4*)(x + (long)row * 1024))[tid];
    float s  = v.x + v.y + v.z + v.w;
    float s2 = v.x*v.x + v.y*v.y + v.z*v.z + v.w*v.w;
    #pragma unroll
    for (int off = 1; off < 64; off <<= 1) {
        s  += __shfl_xor(s, off);
        s2 += __shfl_xor(s2, off);
    }
    __shared__ float red[8];
    const int wave = tid >> 6, lane = tid & 63;
    if (lane == 0) { red[wave] = s; red[4 + wave] = s2; }
    __syncthreads();
    s  = red[0] + red[1] + red[2] + red[3];
    s2 = red[4] + red[5] + red[6] + red[7];
    const float mu   = s * (1.0f / 1024.0f);
    const float var  = s2 * (1.0f / 1024.0f) - mu * mu;
    const float rstd = rsqrtf(var + 1e-5f);
    const int c = tid << 2;
    ushort4 o;
    o.x = f2bf((v.x - mu) * rstd * g[c + 0] + bta[c + 0]);
    o.y = f2bf((v.y - mu) * rstd * g[c + 1] + bta[c + 1]);
    o.z = f2bf((v.z - mu) * rstd * g[c + 2] + bta[c + 2]);
    o.w = f2bf((v.w - mu) * rstd * g[c + 3] + bta[c + 3]);
    ((ushort4*)(out + (long)row * 1024))[tid] = o;
}

// ---------------------------------------------------------------------------
// V transpose per (b,h): (bh, s=2048, d=64) -> (bh, d=64, s=2048), bf16.
// ---------------------------------------------------------------------------
__global__ __launch_bounds__(256) void vtrans_kernel(
    const u16* __restrict__ V, u16* __restrict__ Vt)
{
    __shared__ u16 t[64][72];
    const int bh = blockIdx.y, s0 = blockIdx.x << 6;
    const int tid = threadIdx.x;
    const long base = (long)bh * 2048 * 64;
    const int row = tid >> 2, seg = tid & 3;
    *(uint4*)&t[row][seg << 3] =
        *(const uint4*)(V + base + (long)(s0 + row) * 64 + (seg << 3));
    *(uint4*)&t[row][(seg + 4) << 3] =
        *(const uint4*)(V + base + (long)(s0 + row) * 64 + ((seg + 4) << 3));
    __syncthreads();
    #pragma unroll
    for (int half = 0; half < 2; ++half) {
        const int sl = (seg + (half << 2)) << 3;
        u16 tmp[8];
        #pragma unroll
        for (int j = 0; j < 8; ++j) tmp[j] = t[sl + j][row];
        *(uint4*)(Vt + base + (long)row * 2048 + s0 + sl) = *(uint4*)tmp;
    }
}

// ---------------------------------------------------------------------------
// GEMM: C(N x M) = A(N x K, bf16) * Bt(M x K, bf16)^T. 128xBN tile, BK=32,
// m97 structure: global_load_lds width-16 into unpadded LDS.
// BN=128: 4 waves 2x2 (64x64 each).  BN=64: 4 waves stacked (32x64 each).
// MODE 0: out bf16, fused QKV scatter to (which,B,H,S,hd), bias per segment
// MODE 1: out fp32 row-major, +bias +res
// MODE 2: out bf16 row-major, gelu(v+bias)
// ---------------------------------------------------------------------------
template<int MODE, int BN>
__global__ __launch_bounds__(256) void gemm_kernel(
    const u16* __restrict__ A, const u16* __restrict__ Bt,
    const float* __restrict__ bias0, const float* __restrict__ bias1,
    const float* __restrict__ bias2, const float* __restrict__ res,
    void* __restrict__ outv, int K, int M)
{
    constexpr int MS = (BN == 128) ? 4 : 2;
    __shared__ u16 As[128][32];
    __shared__ u16 Bs[BN][32];
    const int tid  = threadIdx.x;
    const int lane = tid & 63, wave = tid >> 6;
    const int wm = (BN == 128) ? ((wave >> 1) << 6) : (wave << 5);
    const int wn = (BN == 128) ? ((wave & 1) << 6) : 0;
    const int lrow = lane & 15, quad = lane >> 4, kq = quad << 3;
    const long rowbase = (long)blockIdx.y * 128;
    const long colbase = (long)blockIdx.x * BN;

    const int srow = lane >> 2;            // 0..15
    const int sseg = (lane & 3) << 3;
    const u16* ga0 = A + (rowbase + (wave << 5) + srow) * (long)K + sseg;
    const u16* ga1 = ga0 + 16 * (long)K;
    u16* lA0 = &As[(wave << 5)][0];
    u16* lA1 = &As[(wave << 5) + 16][0];
    const u16* gb0;
    const u16* gb1 = nullptr;
    u16* lB0;
    u16* lB1 = nullptr;
    if constexpr (BN == 128) {
        gb0 = Bt + (colbase + (wave << 5) + srow) * (long)K + sseg;
        gb1 = gb0 + 16 * (long)K;
        lB0 = &Bs[(wave << 5)][0];
        lB1 = &Bs[(wave << 5) + 16][0];
    } else {
        gb0 = Bt + (colbase + (wave << 4) + srow) * (long)K + sseg;
        lB0 = &Bs[(wave << 4)][0];
    }

    floatx4 acc[MS][4];
    #pragma unroll
    for (int i = 0; i < MS; ++i)
        #pragma unroll
        for (int j = 0; j < 4; ++j)
            acc[i][j] = floatx4{0.f, 0.f, 0.f, 0.f};

    for (int k0 = 0; k0 < K; k0 += 32) {
        __syncthreads();
        gld_lds16(ga0 + k0, lA0);
        gld_lds16(ga1 + k0, lA1);
        gld_lds16(gb0 + k0, lB0);
        if constexpr (BN == 128) gld_lds16(gb1 + k0, lB1);
        __syncthreads();
        bf16x8 af[MS], bf[4];
        #pragma unroll
        for (int ms = 0; ms < MS; ++ms)
            af[ms] = *(const bf16x8*)&As[wm + (ms << 4) + lrow][kq];
        #pragma unroll
        for (int ns = 0; ns < 4; ++ns)
            bf[ns] = *(const bf16x8*)&Bs[wn + (ns << 4) + lrow][kq];
        #pragma unroll
        for (int ms = 0; ms < MS; ++ms)
            #pragma unroll
            for (int ns = 0; ns < 4; ++ns)
                acc[ms][ns] = __builtin_amdgcn_mfma_f32_16x16x32_bf16(
                    af[ms], bf[ns], acc[ms][ns], 0, 0, 0);
    }

    #pragma unroll
    for (int ms = 0; ms < MS; ++ms) {
        #pragma unroll
        for (int ns = 0; ns < 4; ++ns) {
            const long col = colbase + wn + (ns << 4) + lrow;
            float bv;
            if constexpr (MODE == 0) {
                const int which = (int)(col >> 10);
                const float* bp = which == 0 ? bias0 : (which == 1 ? bias1 : bias2);
                bv = bp[col & 1023];
            } else {
                bv = bias0[col];
            }
            #pragma unroll
            for (int r = 0; r < 4; ++r) {
                const long row = rowbase + wm + (ms << 4) + (quad << 2) + r;
                float v = acc[ms][ns][r] + bv;
                if constexpr (MODE == 0) {
                    const long which = col >> 10;
                    const long b = row >> 11, s = row & 2047;
                    const long h = (col >> 6) & 15, d = col & 63;
                    ((u16*)outv)[which * 4194304 + (((b << 4) + h) * 2048 + s) * 64 + d] = f2bf(v);
                } else if constexpr (MODE == 1) {
                    const long idx = row * M + col;
                    ((float*)outv)[idx] = v + res[idx];
                } else {
                    const float gl = 0.5f * v * (1.0f + erff(v * 0.70710678118f));
                    ((u16*)outv)[row * M + col] = f2bf(gl);
                }
            }
        }
    }
}

// ---------------------------------------------------------------------------
// Flash attention v3. Q,K in (bh, s, 64) bf16; Vt in (bh, 64, s) bf16.
// Block = 128 queries of one (b,h): 4 waves x 2 groups x 16 q.
// K/Vt tiles (64x64) staged in LDS via global_load_lds, XOR-swizzled 16B
// chunks (unpadded staging + conflict-free ds_read_b128). S^T softmax:
// mfma(kf,qf) -> lane owns q=lane&15, 16 keys in regs; in-lane tree + 2
// shfl_xor. P -> A-operand via per-wave LDS round-trip (no barrier).
// ---------------------------------------------------------------------------
__global__ __launch_bounds__(256) void attn_kernel(
    const u16* __restrict__ Q, const u16* __restrict__ Kp,
    const u16* __restrict__ Vt, u16* __restrict__ O)
{
    __shared__ u16 Ks[4096];          // 64 rows x 64, swizzled: 8 KB
    __shared__ u16 Vs[4096];          // 64 d-rows x 64 keys, swizzled: 8 KB
    __shared__ u16 Ps[4][2][16][72];  // wave, group, q, key (padded): 18 KB
    const int tid = threadIdx.x, lane = tid & 63, wave = tid >> 6;
    const int lrow = lane & 15, quad = lane >> 4;
    const int bh = blockIdx.y;
    const long kvbase = (long)bh * 2048 * 64;
    const int qbase = (blockIdx.x << 7) + (wave << 5);

    // --- staging geometry: instr i covers rows 8i..8i+7; lane l -> row
    // 8i + (l>>3), chunk (l&7)^(l>>3) (XOR swizzle). Wave w does i=2w,2w+1.
    const int srow = lane >> 3;
    const int schunk = (lane & 7) ^ srow;
    const int i0 = wave << 1;
    const u16* kg0 = Kp + kvbase + (long)(((i0 << 3) + srow) * 64 + (schunk << 3));
    const u16* kg1 = kg0 + 8 * 64;
    const u16* vg0 = Vt + kvbase + (long)(((i0 << 3) + srow) * 2048 + (schunk << 3));
    const u16* vg1 = vg0 + 8 * 2048;
    u16* lk0 = &Ks[i0 << 9]; u16* lk1 = lk0 + 512;
    u16* lv0 = &Vs[i0 << 9]; u16* lv1 = lv0 + 512;

    // --- Q fragments (global, once) ---
    bf16x8 qf[2][2];
    #pragma unroll
    for (int g = 0; g < 2; ++g)
        #pragma unroll
        for (int h = 0; h < 2; ++h)
            qf[g][h] = *(const bf16x8*)(Q + kvbase +
                (long)(qbase + (g << 4) + lrow) * 64 + (quad << 3) + (h << 5));

    // --- tile-invariant swizzled LDS read offsets (elements) ---
    int aoff[4][2];
    #pragma unroll
    for (int ns = 0; ns < 4; ++ns)
        #pragma unroll
        for (int h = 0; h < 2; ++h)
            aoff[ns][h] = ((ns << 4) + lrow) * 64 +
                          (((quad + (h << 2)) ^ (lrow & 7)) << 3);

    floatx4 oacc[2][4];
    #pragma unroll
    for (int g = 0; g < 2; ++g)
        #pragma unroll
        for (int ns = 0; ns < 4; ++ns)
            oacc[g][ns] = floatx4{0.f, 0.f, 0.f, 0.f};
    float mr[2] = {-3e38f, -3e38f}, lr[2] = {0.f, 0.f};

    for (int kv0 = 0; kv0 < 2048; kv0 += 64) {
        __syncthreads();
        gld_lds16(kg0, lk0);
        gld_lds16(kg1, lk1);
        gld_lds16(vg0 + kv0, lv0);
        gld_lds16(vg1 + kv0, lv1);
        kg0 += 4096; kg1 += 4096;
        __syncthreads();

        // --- QK^T (S^T): C[key][q], lane: q=lrow, keys quad*4+r per ns ---
        floatx4 st[2][4];
        #pragma unroll
        for (int ns = 0; ns < 4; ++ns) {
            const bf16x8 af0 = *(const bf16x8*)&Ks[aoff[ns][0]];
            const bf16x8 af1 = *(const bf16x8*)&Ks[aoff[ns][1]];
            floatx4 z = floatx4{0.f, 0.f, 0.f, 0.f};
            st[0][ns] = __builtin_amdgcn_mfma_f32_16x16x32_bf16(af0, qf[0][0], z, 0, 0, 0);
            st[0][ns] = __builtin_amdgcn_mfma_f32_16x16x32_bf16(af1, qf[0][1], st[0][ns], 0, 0, 0);
            st[1][ns] = __builtin_amdgcn_mfma_f32_16x16x32_bf16(af0, qf[1][0], z, 0, 0, 0);
            st[1][ns] = __builtin_amdgcn_mfma_f32_16x16x32_bf16(af1, qf[1][1], st[1][ns], 0, 0, 0);
        }

        // --- online softmax + P through per-wave LDS ---
        bf16x8 pf[2][2];
        float al[2][4];
        #pragma unroll
        for (int g = 0; g < 2; ++g) {
            float mt = -3e38f;
            #pragma unroll
            for (int ns = 0; ns < 4; ++ns)
                #pragma unroll
                for (int r = 0; r < 4; ++r)
                    mt = fmaxf(mt, st[g][ns][r]);
            mt = fmaxf(mt, __shfl_xor(mt, 16));
            mt = fmaxf(mt, __shfl_xor(mt, 32));
            mt *= 0.125f;
            const float mnew  = fmaxf(mr[g], mt);
            const float alpha = __expf(mr[g] - mnew);
            mr[g] = mnew;
            float rs = 0.f;
            #pragma unroll
            for (int ns = 0; ns < 4; ++ns) {
                float p0 = __expf(st[g][ns][0] * 0.125f - mnew);
                float p1 = __expf(st[g][ns][1] * 0.125f - mnew);
                float p2 = __expf(st[g][ns][2] * 0.125f - mnew);
                float p3 = __expf(st[g][ns][3] * 0.125f - mnew);
                rs += (p0 + p1) + (p2 + p3);
                uint2 w;
                w.x = __builtin_amdgcn_perm(__float_as_uint(p1) + 0x8000u,
                                            __float_as_uint(p0) + 0x8000u, 0x07060302u);
                w.y = __builtin_amdgcn_perm(__float_as_uint(p3) + 0x8000u,
                                            __float_as_uint(p2) + 0x8000u, 0x07060302u);
                *(uint2*)&Ps[wave][g][lrow][(ns << 4) + (quad << 2)] = w;
            }
            rs += __shfl_xor(rs, 16);
            rs += __shfl_xor(rs, 32);
            lr[g] = lr[g] * alpha + rs;
            // A-operand read-back (within-wave; lgkmcnt ordering only)
            pf[g][0] = *(const bf16x8*)&Ps[wave][g][lrow][quad << 3];
            pf[g][1] = *(const bf16x8*)&Ps[wave][g][lrow][(quad << 3) + 32];
            #pragma unroll
            for (int r = 0; r < 4; ++r)
                al[g][r] = __shfl(alpha, (quad << 2) + r);
        }

        // --- PV: O[q][d] += P * Vt ---
        #pragma unroll
        for (int ns = 0; ns < 4; ++ns) {
            const bf16x8 vf0 = *(const bf16x8*)&Vs[aoff[ns][0]];
            const bf16x8 vf1 = *(const bf16x8*)&Vs[aoff[ns][1]];
            #pragma unroll
            for (int g = 0; g < 2; ++g) {
                #pragma unroll
                for (int r = 0; r < 4; ++r) oacc[g][ns][r] *= al[g][r];
                oacc[g][ns] = __builtin_amdgcn_mfma_f32_16x16x32_bf16(
                    pf[g][0], vf0, oacc[g][ns], 0, 0, 0);
                oacc[g][ns] = __builtin_amdgcn_mfma_f32_16x16x32_bf16(
                    pf[g][1], vf1, oacc[g][ns], 0, 0, 0);
            }
        }
    }

    const int b = bh >> 4, h = bh & 15;
    #pragma unroll
    for (int g = 0; g < 2; ++g) {
        float linv[4];
        #pragma unroll
        for (int r = 0; r < 4; ++r)
            linv[r] = 1.0f / __shfl(lr[g], (quad << 2) + r);
        #pragma unroll
        for (int ns = 0; ns < 4; ++ns)
            #pragma unroll
            for (int r = 0; r < 4; ++r) {
                const int q = qbase + (g << 4) + (quad << 2) + r;
                const long token = (long)b * 2048 + q;
                O[token * 1024 + (h << 6) + (ns << 4) + lrow] =
                    f2bf(oacc[g][ns][r] * linv[r]);
            }
    }
}

// ---------------------------------------------------------------------------
// Host launcher
// ---------------------------------------------------------------------------
extern "C" void kernel_launch(void* const* d_in, const int* in_sizes, int n_in,
                              void* d_out, int out_size, void* d_ws, size_t ws_size,
                              hipStream_t stream)
{
    const float* x     = (const float*)d_in[0];
    const float* ln1_g = (const float*)d_in[1];
    const float* ln1_b = (const float*)d_in[2];
    const float* wq    = (const float*)d_in[3];
    const float* bq    = (const float*)d_in[4];
    const float* wk    = (const float*)d_in[5];
    const float* bk    = (const float*)d_in[6];
    const float* wv    = (const float*)d_in[7];
    const float* bv    = (const float*)d_in[8];
    const float* wo    = (const float*)d_in[9];
    const float* bo    = (const float*)d_in[10];
    const float* w1    = (const float*)d_in[11];
    const float* b1    = (const float*)d_in[12];
    const float* w2    = (const float*)d_in[13];
    const float* b2    = (const float*)d_in[14];
    const float* ln2_g = (const float*)d_in[15];
    const float* ln2_b = (const float*)d_in[16];
    float* out = (float*)d_out;

    char* w = (char*)d_ws;
    const size_t MB = 1024 * 1024;
    u16*   wqkvt = (u16*)(w + 0);        // [0,6) MB: wq^T|wk^T|wv^T
    u16*   wot   = (u16*)(w + 6  * MB);  // [6,8)
    u16*   w1t   = (u16*)(w + 8  * MB);  // [8,16)
    u16*   w2t   = (u16*)(w + 16 * MB);  // [16,24)
    u16*   h1    = (u16*)(w + 24 * MB);  // [24,32): ln1 out / attn out / ln2 out
    u16*   qkvb  = (u16*)(w + 32 * MB);  // [32,56): Q|K|V (bh,s,d)
    u16*   vtb   = (u16*)(w + 56 * MB);  // [56,64): V^T (bh,d,s)
    float* x1    = (float*)(w + 64 * MB);// [64,80): fp32 residual-1
    u16*   ffb   = (u16*)(w + 32 * MB);  // [32,64): FF hidden (reuses qkv/vtb)
    u16*   qb = qkvb;
    u16*   kb = qkvb + 4194304;
    u16*   vb = qkvb + 8388608;

    const dim3 tb(32, 8);
    transpose_cvt<<<dim3(32, 32),  tb, 0, stream>>>(wq, wqkvt,           1024, 1024);
    transpose_cvt<<<dim3(32, 32),  tb, 0, stream>>>(wk, wqkvt + 1048576, 1024, 1024);
    transpose_cvt<<<dim3(32, 32),  tb, 0, stream>>>(wv, wqkvt + 2097152, 1024, 1024);
    transpose_cvt<<<dim3(32, 32),  tb, 0, stream>>>(wo, wot,             1024, 1024);
    transpose_cvt<<<dim3(128, 32), tb, 0, stream>>>(w1, w1t,             1024, 4096);
    transpose_cvt<<<dim3(32, 128), tb, 0, stream>>>(w2, w2t,             4096, 1024);

    ln_kernel<<<4096, 256, 0, stream>>>(x, ln1_g, ln1_b, h1);

    gemm_kernel<0, 128><<<dim3(24, 32), 256, 0, stream>>>(
        h1, wqkvt, bq, bk, bv, nullptr, qkvb, 1024, 3072);

    vtrans_kernel<<<dim3(32, 32), 256, 0, stream>>>(vb, vtb);

    attn_kernel<<<dim3(16, 32), 256, 0, stream>>>(qb, kb, vtb, h1);

    gemm_kernel<1, 64><<<dim3(16, 32), 256, 0, stream>>>(
        h1, wot, bo, nullptr, nullptr, x, x1, 1024, 1024);

    ln_kernel<<<4096, 256, 0, stream>>>(x1, ln2_g, ln2_b, h1);

    gemm_kernel<2, 128><<<dim3(32, 32), 256, 0, stream>>>(
        h1, w1t, b1, nullptr, nullptr, nullptr, ffb, 1024, 4096);

    gemm_kernel<1, 64><<<dim3(16, 32), 256, 0, stream>>>(
        ffb, w2t, b2, nullptr, nullptr, x1, out, 4096, 1024);
}